// Round 9
// baseline (138.546 us; speedup 1.0000x reference)
//
#include <hip/hip_runtime.h>
#include <hip/hip_bf16.h>
#include <math.h>

// TransitionLoss on MI355X (gfx950), v9 — two dispatches, zero cross-lane
// reduction chains (R8 post-mortem: ds_bpermute chains were 90% of the time).
// K1: sim = f f^T via split-fp16 MFMA (hi*hi + hi*lo + lo*hi, err ~1e-4).
// K2: one block per (target,sub) pair: thread-per-row chunked scans
//     (A: masked online LSE -> M,L; B: w = max(S-q); C: X fp16 in LDS),
//     then Gram G = X X^T via MFMA + eval, one atomicAdd per block.
// Dedup: loss depends only on (target,sub) -> 64 pairs, weight=multiplicity.

constexpr int kB = 256;
constexpr int kD = 512;
constexpr float NEG_BIG = -3.0e38f;

typedef _Float16 f16x8 __attribute__((ext_vector_type(8)));
typedef _Float16 f16x4 __attribute__((ext_vector_type(4)));
typedef float f32x16 __attribute__((ext_vector_type(16)));

// ---------------- K1: sim via split-fp16 MFMA ----------------
constexpr int S_PAD = 520;                 // f16 row stride (1040B: 16B-aligned, 4-way banks)
constexpr int SM1_A = 32 * S_PAD * 2;      // 33,280 B per array
constexpr int SM1_TOTAL = 4 * SM1_A;       // 133,120 B

__global__ __launch_bounds__(256)
void simMfmaKernel(const float* __restrict__ f, float* __restrict__ sim,
                   float* __restrict__ out) {
  extern __shared__ char sm1[];
  _Float16* Ahi = (_Float16*)sm1;
  _Float16* Alo = (_Float16*)(sm1 + SM1_A);
  _Float16* Bhi = (_Float16*)(sm1 + 2 * SM1_A);
  _Float16* Blo = (_Float16*)(sm1 + 3 * SM1_A);
  const int tid = threadIdx.x;
  const int bi = blockIdx.x >> 3, bj = blockIdx.x & 7;   // 32x32 tile (bi,bj)
  // stage + split both 32-row bands (coalesced float4 reads)
  for (int j = tid; j < 4096; j += 256) {
    const int row = j >> 7, kc = (j & 127) << 2;
    float4 va = *(const float4*)(f + (size_t)(bi * 32 + row) * kD + kc);
    float4 vb = *(const float4*)(f + (size_t)(bj * 32 + row) * kD + kc);
    f16x4 ah, al, bh, bl;
#pragma unroll
    for (int e = 0; e < 4; e++) {
      float x = (&va.x)[e];
      _Float16 h = (_Float16)x;
      ah[e] = h; al[e] = (_Float16)(x - (float)h);
      float y = (&vb.x)[e];
      _Float16 g = (_Float16)y;
      bh[e] = g; bl[e] = (_Float16)(y - (float)g);
    }
    *(f16x4*)(Ahi + row * S_PAD + kc) = ah;
    *(f16x4*)(Alo + row * S_PAD + kc) = al;
    *(f16x4*)(Bhi + row * S_PAD + kc) = bh;
    *(f16x4*)(Blo + row * S_PAD + kc) = bl;
  }
  __syncthreads();
  const int lane = tid & 63, wave = tid >> 6;
  const int l31 = lane & 31, kg = lane >> 5;
  f32x16 acc;
#pragma unroll
  for (int g = 0; g < 16; g++) acc[g] = 0.f;
  const int kb0 = wave * 128;                 // split-K across 4 waves
#pragma unroll
  for (int st = 0; st < 8; st++) {
    const int k = kb0 + st * 16 + kg * 8;
    f16x8 ah = *(const f16x8*)(Ahi + l31 * S_PAD + k);
    f16x8 al = *(const f16x8*)(Alo + l31 * S_PAD + k);
    f16x8 bh = *(const f16x8*)(Bhi + l31 * S_PAD + k);
    f16x8 bl = *(const f16x8*)(Blo + l31 * S_PAD + k);
    acc = __builtin_amdgcn_mfma_f32_32x32x16_f16(ah, bh, acc, 0, 0, 0);
    acc = __builtin_amdgcn_mfma_f32_32x32x16_f16(ah, bl, acc, 0, 0, 0);
    acc = __builtin_amdgcn_mfma_f32_32x32x16_f16(al, bh, acc, 0, 0, 0);
  }
  __syncthreads();                            // reuse LDS for split-K reduce
  float* red = (float*)sm1;                   // [4][1024]
#pragma unroll
  for (int g = 0; g < 16; g++) {
    const int rr = 4 * kg + (g & 3) + ((g >> 2) << 3);  // C/D row mapping
    red[wave * 1024 + (rr << 5) + l31] = acc[g];
  }
  __syncthreads();
  for (int j = tid; j < 1024; j += 256) {
    float s2 = (red[j] + red[1024 + j]) + (red[2048 + j] + red[3072 + j]);
    sim[(size_t)(bi * 32 + (j >> 5)) * kB + bj * 32 + (j & 31)] = s2;
  }
  if (blockIdx.x == 0 && tid == 0) out[0] = 0.f;   // overwrite 0xAA poison
}

// ---------------- K2: per-pair scans + Gram ----------------
constexpr int PB_SC  = 0;        // [256][33] f32 chunk = 33,792
constexpr int PB_M   = 33792;    // [256] f32
constexpr int PB_L   = 34816;
constexpr int PB_Q   = 35840;
constexpr int PB_W   = 36864;
constexpr int PB_E   = 37888;    // [2][256] f32
constexpr int PB_F   = 39936;    // [2][256] f32
constexpr int PB_CAT = 41984;    // u8[256]
constexpr int PB_RNK = 42240;    // u8[256]
constexpr int PB_CNT = 42496;    // int[4]
constexpr int PB_RED = 42512;    // f32[8] (+pad)
constexpr int PB_X0  = 42560;    // fp16, cap 44,032 (worst 160x136x2 = 43,520)
constexpr int PB_X1  = 86592;    // fp16, cap 44,032
constexpr int PB_TOTAL = 130624; // <= 163,840

__global__ __launch_bounds__(512)
void pairKernel(const float* __restrict__ sim, const int* __restrict__ tgt,
                const int* __restrict__ sub, float* __restrict__ out) {
  extern __shared__ char sm[];
  float* SC = (float*)(sm + PB_SC);
  float* Mv = (float*)(sm + PB_M);
  float* Lv = (float*)(sm + PB_L);
  float* Qv = (float*)(sm + PB_Q);
  float* Wv = (float*)(sm + PB_W);
  float* Ep = (float*)(sm + PB_E);
  float* Fp = (float*)(sm + PB_F);
  unsigned char* CAT = (unsigned char*)(sm + PB_CAT);
  unsigned char* RNK = (unsigned char*)(sm + PB_RNK);
  int* CNT = (int*)(sm + PB_CNT);
  float* RED = (float*)(sm + PB_RED);
  _Float16* X0 = (_Float16*)(sm + PB_X0);
  _Float16* X1 = (_Float16*)(sm + PB_X1);

  const int p = blockIdx.x, t = p >> 1, s = p & 1;
  const int tid = threadIdx.x, lane = tid & 63, wave = tid >> 6;

  if (tid < 256) {
    bool pos = (tgt[tid] == t), intra = (sub[tid] == s);
    CAT[tid] = (unsigned char)(pos ? (intra ? 0 : 1) : (intra ? 2 : 3)); // mpi mpc mni mnc
  }
  __syncthreads();
  if (wave == 0) {   // rank-within-category + counts via ballots
    int base[4] = {0, 0, 0, 0};
    for (int ch = 0; ch < 4; ch++) {
      const int c = ch * 64 + lane;
      const int cat = CAT[c];
#pragma unroll
      for (int l = 0; l < 4; l++) {
        bool fl = (cat == l);
        unsigned long long mm = __ballot(fl);
        if (fl) RNK[c] = (unsigned char)(base[l] + __popcll(mm & ((1ull << lane) - 1ull)));
        base[l] += __popcll(mm);
      }
    }
    if (lane == 0) { CNT[0] = base[0]; CNT[1] = base[1]; CNT[2] = base[2]; CNT[3] = base[3]; }
  }
  __syncthreads();
  const int c0n = CNT[0], c1n = CNT[1], c2n = CNT[2], c3n = CNT[3];
  const int mult = c0n;                    // anchors with this (t,s)
  if (mult == 0) return;
  if (tid == 0 && c1n == 0)                // pos part, empty K: x=1e-6 each
    atomicAdd(out, (float)mult * (0.5f - 1e-6f) * (1.f / 256.f));
  const int nR0 = c2n, nK0 = c3n, nR1 = c0n, nK1 = c1n;
  const float sc0 = (nR0 > 0 && nK0 > 0) ? (float)mult / ((float)nR0 * nR0 * 256.f) : 0.f;
  const float sc1 = (nK1 > 0) ? (float)mult / ((float)nR1 * nR1 * 256.f) : 0.f;
  if (sc0 == 0.f && sc1 == 0.f) return;
  const int KP0 = (nK0 + 15) & ~15, SKh0 = KP0 + 8, nT0 = sc0 != 0.f ? ((nR0 + 31) >> 5) : 0;
  const int KP1 = (nK1 + 15) & ~15, SKh1 = KP1 + 8, nT1 = sc1 != 0.f ? ((nR1 + 31) >> 5) : 0;

  // per-thread 256-bit mask (register), kappa = CAT[r]^1 — same mask for
  // stats (M,L), w, and X-cols of the part row r belongs to.
  unsigned bits[8];
  bool isR = false; int partR = 0; bool liveP = false;
  if (tid < 256) {
    const int myCat = CAT[tid], kap = myCat ^ 1;
    isR = (myCat == 0) || (myCat == 2);
    partR = (myCat == 0) ? 1 : 0;
    liveP = isR && ((partR == 1) ? (sc1 != 0.f) : (sc0 != 0.f));
#pragma unroll
    for (int j = 0; j < 8; j++) {
      unsigned b = 0;
      for (int i = 0; i < 32; i++) b |= (CAT[j * 32 + i] == kap) ? (1u << i) : 0u;
      bits[j] = b;
    }
  }
  // zero X (incl. pads) + E/F
  for (int j = tid; j < 22016; j += 512) ((unsigned*)(sm + PB_X0))[j] = 0;
  if (tid < 256) { Ep[tid] = 0.f; Ep[256 + tid] = 0.f; Fp[tid] = 0.f; Fp[256 + tid] = 0.f; }

#define STAGE_CHUNK(CH)                                                        \
  for (int j = tid; j < 2048; j += 512) {                                      \
    const int rr = j >> 3, cw = (j & 7) << 2;                                  \
    float4 v = *(const float4*)(sim + (size_t)rr * kB + (CH) * 32 + cw);       \
    SC[rr * 33 + cw + 0] = v.x; SC[rr * 33 + cw + 1] = v.y;                    \
    SC[rr * 33 + cw + 2] = v.z; SC[rr * 33 + cw + 3] = v.w;                    \
  }

  // ---- Scan A: masked online logsumexp -> M, L ----
  float m = NEG_BIG, ssum = 0.f;
  for (int ch = 0; ch < 8; ch++) {
    __syncthreads();
    STAGE_CHUNK(ch);
    __syncthreads();
    if (tid < 256) {
      const unsigned b = bits[ch];
      for (int i = 0; i < 32; i++) if ((b >> i) & 1) {
        const float v = SC[tid * 33 + i];
        const float nm = fmaxf(m, v);
        ssum = ssum * __expf(m - nm) + __expf(v - nm);
        m = nm;
      }
    }
  }
  __syncthreads();
  if (tid < 256) { Mv[tid] = m; Lv[tid] = __logf(ssum); }
  __syncthreads();
  if (tid < 256) Qv[tid] = 0.5f * (Mv[tid] + Lv[tid]);

  // ---- Scan B: w[r] = max_k (S - q) over K-cols ----
  float wv = NEG_BIG;
  for (int ch = 0; ch < 8; ch++) {
    __syncthreads();
    STAGE_CHUNK(ch);
    __syncthreads();
    if (tid < 256 && isR) {
      const unsigned b = bits[ch];
      for (int i = 0; i < 32; i++) if ((b >> i) & 1)
        wv = fmaxf(wv, SC[tid * 33 + i] - Qv[ch * 32 + i]);
    }
  }
  __syncthreads();
  if (tid < 256 && liveP) {
    Wv[tid] = wv;
    const float u = Mv[tid] + Lv[tid];
    const int ri = RNK[tid];
    Ep[partR * 256 + ri] = __expf(0.5f * (wv - u));
    Fp[partR * 256 + ri] = __expf(0.5f * wv);
  }

  // ---- Scan C: X = fp16(exp(S - q - w)) compacted in LDS ----
  for (int ch = 0; ch < 8; ch++) {
    __syncthreads();
    STAGE_CHUNK(ch);
    __syncthreads();
    if (tid < 256 && liveP) {
      _Float16* xrow = ((partR == 1) ? X1 : X0)
                     + (int)RNK[tid] * ((partR == 1) ? SKh1 : SKh0);
      const unsigned b = bits[ch];
      for (int i = 0; i < 32; i++) if ((b >> i) & 1) {
        const int cc = ch * 32 + i;
        xrow[(int)RNK[cc]] = (_Float16)__expf(SC[tid * 33 + i] - Qv[cc] - wv);
      }
    }
  }
  __syncthreads();

  // ---- Gram tiles (32x32) via MFMA + eval ----
  const int J0 = nT0 * nT0, J = J0 + nT1 * nT1;
  float res = 0.f;
  const int l31 = lane & 31, kg = lane >> 5;
  for (int job = wave; job < J; job += 8) {
    int part, tt;
    if (job < J0) { part = 0; tt = job; }
    else { part = 1; tt = job - J0; }
    const int nT = part ? nT1 : nT0, nRv = part ? nR1 : nR0;
    const int KP = part ? KP1 : KP0, SKh = part ? SKh1 : SKh0;
    const _Float16* Xp = part ? X1 : X0;
    const float sc = part ? sc1 : sc0;
    const int r0t = (tt / nT) << 5, c0t = (tt % nT) << 5;
    const _Float16* pa = Xp + (r0t + l31) * SKh + 8 * kg;
    const _Float16* pb = Xp + (c0t + l31) * SKh + 8 * kg;
    f32x16 acc;
#pragma unroll
    for (int g = 0; g < 16; g++) acc[g] = 0.f;
    for (int kb = 0; kb < KP; kb += 16)
      acc = __builtin_amdgcn_mfma_f32_32x32x16_f16(*(const f16x8*)(pa + kb),
                                                   *(const f16x8*)(pb + kb), acc, 0, 0, 0);
    const int cc = c0t + l31;
    float tsum = 0.f;
    if (cc < nRv) {
      const float Fc = Fp[part * 256 + cc];
      const int rb = r0t + 4 * kg;
#pragma unroll
      for (int g = 0; g < 16; g++) {
        const int rr2 = rb + (g & 3) + ((g >> 2) << 3);  // C/D: col=lane&31
        if (rr2 < nRv) {
          float x = Ep[part * 256 + rr2] * Fc * sqrtf(acc[g]);
          x = fmaxf(x, 1e-6f);                            // tr clip 1e-12
          tsum += part ? fmaxf(0.5f - x, 0.f) : fmaxf(x - 0.2f, 0.f);
        }
      }
    }
    res += tsum * sc;
  }
#pragma unroll
  for (int o = 32; o >= 1; o >>= 1) res += __shfl_xor(res, o, 64);
  if (lane == 0) RED[wave] = res;
  __syncthreads();
  if (tid == 0) {
    float tot = 0.f;
#pragma unroll
    for (int w2 = 0; w2 < 8; w2++) tot += RED[w2];
    atomicAdd(out, tot);
  }
#undef STAGE_CHUNK
}

extern "C" void kernel_launch(void* const* d_in, const int* in_sizes, int n_in,
                              void* d_out, int out_size, void* d_ws, size_t ws_size,
                              hipStream_t stream) {
  (void)in_sizes; (void)n_in; (void)out_size; (void)ws_size;
  const float* feature = (const float*)d_in[0];
  const int* subv = (const int*)d_in[1];
  const int* tgtv = (const int*)d_in[2];
  float* out = (float*)d_out;
  float* sim = (float*)d_ws;    // 256*256 f32

  (void)hipFuncSetAttribute(reinterpret_cast<const void*>(simMfmaKernel),
                            hipFuncAttributeMaxDynamicSharedMemorySize, SM1_TOTAL);
  (void)hipFuncSetAttribute(reinterpret_cast<const void*>(pairKernel),
                            hipFuncAttributeMaxDynamicSharedMemorySize, PB_TOTAL);

  simMfmaKernel<<<64, 256, SM1_TOTAL, stream>>>(feature, sim, out);
  pairKernel<<<64, 512, PB_TOTAL, stream>>>(sim, tgtv, subv, out);
}